// Round 7
// baseline (2579.030 us; speedup 1.0000x reference)
//
#include <hip/hip_runtime.h>

#define BT 4096
#define H  2048
#define V  32000
#define BM 256
#define BN 256
#define BKB 128                   /* fp8 bytes per K-tile row */
#define KT (H / BKB)              /* 16 K-tiles */
#define NTILES (V / BN)           /* 125 */
#define MTILES (BT / BM)          /* 16 */
#define NWG (MTILES * NTILES)     /* 2000, % 8 == 0 -> bijective XCD swizzle */
#define IGNORE_INDEX (-100)

typedef int   v8i   __attribute__((ext_vector_type(8)));
typedef float f32x4 __attribute__((ext_vector_type(4)));

#define SCALE_ONE 0x7F7F7F7F        /* E8M0 127 = 2^0 in every byte */
#define UNSCALE   (1.0f / 65536.0f) /* inputs pre-scaled by 2^8 each */

#define BAR()   __builtin_amdgcn_s_barrier()
#define SB0()   __builtin_amdgcn_sched_barrier(0)
#define LGKM0() asm volatile("s_waitcnt lgkmcnt(0)" ::: "memory")
#define VMC(N)  asm volatile("s_waitcnt vmcnt(" #N ")" ::: "memory")

__device__ inline void load_lds16(const void* g, void* l) {
  __builtin_amdgcn_global_load_lds(
      (const __attribute__((address_space(1))) unsigned int*)g,
      (__attribute__((address_space(3))) unsigned int*)l,
      16, 0, 0);
}

// ------------------------------------------- fp32 -> fp8 e4m3, FRAG-PACKED
// Coalesced: wave-local LDS transpose. Per task (row-group g, K-tile kt):
// stage 16 rows x 128 floats coalesced, then each lane gathers its 32 floats
// from LDS and writes the packed 2KB block:
//   byte [c*1024 + lane*16 + b] = fp8( in[g*16 + (lane&15)]
//                                       [kt*128 + (lane>>4)*32 + c*16 + b] )
__global__ __launch_bounds__(256)
void cvt_pack_kernel(const float* __restrict__ in, unsigned char* __restrict__ out,
                     int tasks) {
  __shared__ float ld[4][16][132];           // +4 pad breaks row-bank alias
  const int wv = threadIdx.x >> 6, lane = threadIdx.x & 63;
  const int task = blockIdx.x * 4 + wv;
  if (task >= tasks) return;                 // wave-divergent ok: no block bar
  const int g = task >> 4, kt = task & 15;   // KT = 16
  const float* src = in + (size_t)(g * 16) * H + kt * 128;
#pragma unroll
  for (int i = 0; i < 8; ++i) {              // 512 float4, coalesced
    int idx = i * 64 + lane;
    int r = idx >> 5, c = idx & 31;
    float4 v = *(const float4*)(src + (size_t)r * H + c * 4);
    *(float4*)&ld[wv][r][c * 4] = v;
  }
  LGKM0();                                   // cross-lane LDS visibility
  const int row = lane & 15, kb = (lane >> 4) * 32;
  int p[8];
#pragma unroll
  for (int u = 0; u < 8; ++u) {
    float4 x = *(const float4*)&ld[wv][row][kb + u * 4];
    int v = 0;
    v = __builtin_amdgcn_cvt_pk_fp8_f32(x.x * 256.f, x.y * 256.f, v, false);
    v = __builtin_amdgcn_cvt_pk_fp8_f32(x.z * 256.f, x.w * 256.f, v, true);
    p[u] = v;
  }
  unsigned char* dst = out + ((size_t)g * KT + kt) * 2048 + lane * 16;
  int4 lo; lo.x = p[0]; lo.y = p[1]; lo.z = p[2]; lo.w = p[3];
  int4 hi; hi.x = p[4]; hi.y = p[5]; hi.z = p[6]; hi.w = p[7];
  *(int4*)dst          = lo;                 // plane c=0
  *(int4*)(dst + 1024) = hi;                 // plane c=1
}

// --------------------------------------------------------------------------
// 256x256-tile, 8-wave (2x4), MX-fp8 16x16x128 MFMA.
// Memory plan = R3/R5/R6 (proven: FETCH ~16MB, 0 conflicts): packed
// operands, contiguous-1KB global_load_lds staging, linear frag-contiguous
// LDS, frag read = base + lane*16 (+1024).
// Occupancy plan R7: SINGLE-buffered LDS (As+Bs = 64KB, block total 73KB)
// -> 2 blocks/CU, 16 waves/CU, 4 waves/SIMD. R0/R5/R6 showed phase
// structure is a non-lever at 1 block/CU (31% MfmaUtil invariant); the
// co-resident anti-phased block provides the cross-wave overlap that
// barrier-locked waves cannot (m114).
// Serial loop per K-tile (race-free by construction):
//   VMC(0) ; bar ; [16 frag reads + 32 MFMA free-sched] ; bar ; stage(kt+1)
// stage->read: own VMC(0) + bar covers all waves' staging. read->overwrite:
// reads drained (MFMA operands, lgkm) before bar; stage issued after bar.
// --------------------------------------------------------------------------
union frag_u { v8i v; int4 h[2]; };

#define MF(C, A, B)                                                         \
  (C) = __builtin_amdgcn_mfma_scale_f32_16x16x128_f8f6f4(                   \
      (A).v, (B).v, (C), 0, 0, 0, SCALE_ONE, 0, SCALE_ONE)

__global__ __launch_bounds__(512, 4)
void gemm_lse_kernel(const unsigned char* __restrict__ Af8,
                     const unsigned char* __restrict__ Bf8,
                     const int* __restrict__ tgt,
                     float* __restrict__ pm, float* __restrict__ pl,
                     float* __restrict__ tl) {
  __shared__ __align__(16) unsigned char As[32768];  // 32 KB (single buffer)
  __shared__ __align__(16) unsigned char Bs[32768];  // 32 KB
  __shared__ float red_m[4][BM];
  __shared__ float red_l[4][BM];
  __shared__ int   stgt[BM];

  // T1 bijective XCD swizzle (2000 % 8 == 0), mt fastest within an XCD:
  // 16 consecutive blocks share one 512KB B-panel (L2-resident); A via L3.
  const int wgid = ((int)blockIdx.x & 7) * (NWG / 8) + ((int)blockIdx.x >> 3);
  const int mt = wgid & (MTILES - 1);
  const int nt = wgid / MTILES;
  const int m0 = mt * BM;
  const int n0 = nt * BN;

  const int tid  = threadIdx.x;
  const int lane = tid & 63;
  const int w    = tid >> 6;   // wave 0..7
  const int wr   = w >> 2;     // 0..1 : rows [wr*128, +128)
  const int wc   = w & 3;      // 0..3 : cols [wc*64, +64)
  const int lm   = lane & 15;
  const int q    = lane >> 4;

  if (tid < BM) stgt[tid] = tgt[m0 + tid];
  __syncthreads();  // drains vmcnt before counted staging begins

  // packed source: row-group (m0/16 + hf*8 + w), K-tile kt, 2KB contiguous.
  const unsigned char* aSrc = Af8 + (size_t)(m0 / 16) * KT * 2048;
  const unsigned char* bSrc = Bf8 + (size_t)(n0 / 16) * KT * 2048;

  auto stageA = [&](int hf, int kt) {
    const unsigned char* s = aSrc + ((size_t)(hf * 8 + w) * KT + kt) * 2048;
    unsigned char* d = As + (hf * 8 + w) * 2048;
    load_lds16(s, d);               // plane 0 (contiguous 1KB)
    load_lds16(s + 1024, d + 1024); // plane 1 (contiguous 1KB)
  };
  auto stageB = [&](int hf, int kt) {
    const unsigned char* s = bSrc + ((size_t)(hf * 8 + w) * KT + kt) * 2048;
    unsigned char* d = Bs + (hf * 8 + w) * 2048;
    load_lds16(s, d);
    load_lds16(s + 1024, d + 1024);
  };

  // fragment reads: one per-lane address, immediate offsets only.
  const unsigned char* aRd = As + lane * 16;
  const unsigned char* bRd = Bs + lane * 16;

  auto ldA = [&](frag_u& f, int i) {
    const unsigned char* p = aRd + (wr * 8 + i) * 2048;
    f.h[0] = *(const int4*)(p);
    f.h[1] = *(const int4*)(p + 1024);
  };
  auto ldB = [&](frag_u& f, int j) {
    const unsigned char* p = bRd + (wc * 4 + j) * 2048;
    f.h[0] = *(const int4*)(p);
    f.h[1] = *(const int4*)(p + 1024);
  };

  f32x4 acc[8][4];
#pragma unroll
  for (int a = 0; a < 8; ++a)
#pragma unroll
    for (int b = 0; b < 4; ++b) acc[a][b] = (f32x4){0.f, 0.f, 0.f, 0.f};

  frag_u fa0, fa1, fa2, fa3, fb0, fb1, fb2, fb3;

  // ---- prologue: stage K-tile 0
  stageA(0, 0); stageA(1, 0); stageB(0, 0); stageB(1, 0);

#pragma unroll 1
  for (int kt = 0; kt < KT; ++kt) {
    VMC(0);                                  // all 8 own staging loads landed
    SB0(); BAR(); SB0();                     // -> every wave's stage landed

    ldA(fa0, 0); ldA(fa1, 1); ldA(fa2, 2); ldA(fa3, 3);
    ldB(fb0, 0); ldB(fb1, 1); ldB(fb2, 2); ldB(fb3, 3);
    __builtin_amdgcn_s_setprio(1);
    MF(acc[0][0], fa0, fb0); MF(acc[1][0], fa1, fb0);
    MF(acc[2][0], fa2, fb0); MF(acc[3][0], fa3, fb0);
    MF(acc[0][1], fa0, fb1); MF(acc[1][1], fa1, fb1);
    MF(acc[2][1], fa2, fb1); MF(acc[3][1], fa3, fb1);
    MF(acc[0][2], fa0, fb2); MF(acc[1][2], fa1, fb2);
    MF(acc[2][2], fa2, fb2); MF(acc[3][2], fa3, fb2);
    MF(acc[0][3], fa0, fb3); MF(acc[1][3], fa1, fb3);
    MF(acc[2][3], fa2, fb3); MF(acc[3][3], fa3, fb3);
    __builtin_amdgcn_s_setprio(0);
    ldA(fa0, 4); ldA(fa1, 5); ldA(fa2, 6); ldA(fa3, 7);
    __builtin_amdgcn_s_setprio(1);
    MF(acc[4][0], fa0, fb0); MF(acc[5][0], fa1, fb0);
    MF(acc[6][0], fa2, fb0); MF(acc[7][0], fa3, fb0);
    MF(acc[4][1], fa0, fb1); MF(acc[5][1], fa1, fb1);
    MF(acc[6][1], fa2, fb1); MF(acc[7][1], fa3, fb1);
    MF(acc[4][2], fa0, fb2); MF(acc[5][2], fa1, fb2);
    MF(acc[6][2], fa2, fb2); MF(acc[7][2], fa3, fb2);
    MF(acc[4][3], fa0, fb3); MF(acc[5][3], fa1, fb3);
    MF(acc[6][3], fa2, fb3); MF(acc[7][3], fa3, fb3);
    __builtin_amdgcn_s_setprio(0);

    LGKM0();                                 // own reads drained (already by MFMA deps)
    SB0(); BAR(); SB0();                     // -> all waves done reading

    if (kt + 1 < KT) {                       // overwrite is now safe
      stageA(0, kt + 1); stageA(1, kt + 1);
      stageB(0, kt + 1); stageB(1, kt + 1);
    }
  }

  __syncthreads();

  // ---- target-logit extraction (C layout: col=lane&15, row=q*4+reg)
#pragma unroll
  for (int ai = 0; ai < 8; ++ai) {
#pragma unroll
    for (int r = 0; r < 4; ++r) {
      int row_local = wr * 128 + ai * 16 + q * 4 + r;
      int c = stgt[row_local] - n0 - wc * 64;
      if ((unsigned)c < 64u && (c & 15) == lm) {
        int bj = c >> 4;
        float v = bj == 0 ? acc[ai][0][r]
                : bj == 1 ? acc[ai][1][r]
                : bj == 2 ? acc[ai][2][r]
                :           acc[ai][3][r];
        tl[m0 + row_local] = v * UNSCALE;
      }
    }
  }

  // ---- per-row (max, sumexp) over this wave's 64 columns
#pragma unroll
  for (int ai = 0; ai < 8; ++ai) {
#pragma unroll
    for (int r = 0; r < 4; ++r) {
      float v0 = acc[ai][0][r] * UNSCALE;
      float v1 = acc[ai][1][r] * UNSCALE;
      float v2 = acc[ai][2][r] * UNSCALE;
      float v3 = acc[ai][3][r] * UNSCALE;
      float mx = fmaxf(fmaxf(v0, v1), fmaxf(v2, v3));
#pragma unroll
      for (int off = 1; off < 16; off <<= 1) mx = fmaxf(mx, __shfl_xor(mx, off));
      float s = __expf(v0 - mx) + __expf(v1 - mx) + __expf(v2 - mx) + __expf(v3 - mx);
#pragma unroll
      for (int off = 1; off < 16; off <<= 1) s += __shfl_xor(s, off);
      if (lm == 0) {
        int row_local = wr * 128 + ai * 16 + q * 4 + r;
        red_m[wc][row_local] = mx;
        red_l[wc][row_local] = s;
      }
    }
  }
  __syncthreads();
  if (tid < BM) {
    float M = fmaxf(fmaxf(red_m[0][tid], red_m[1][tid]),
                    fmaxf(red_m[2][tid], red_m[3][tid]));
    float L = red_l[0][tid] * __expf(red_m[0][tid] - M)
            + red_l[1][tid] * __expf(red_m[1][tid] - M)
            + red_l[2][tid] * __expf(red_m[2][tid] - M)
            + red_l[3][tid] * __expf(red_m[3][tid] - M);
    long idx = (long)nt * BT + (m0 + tid);
    pm[idx] = M;
    pl[idx] = L;
  }
}

// -------------------------------------------- combine partials, wave per row
__global__ __launch_bounds__(256)
void row_lse_kernel(const float* __restrict__ pm, const float* __restrict__ pl,
                    const float* __restrict__ tl, const int* __restrict__ tgt,
                    float* __restrict__ rl) {
  int row  = blockIdx.x * 4 + (threadIdx.x >> 6);
  int lane = threadIdx.x & 63;
  float M = -__builtin_inff();
  float L = 0.f;
  for (int t = lane; t < NTILES; t += 64) {
    float m2 = pm[(long)t * BT + row];
    float l2 = pl[(long)t * BT + row];
    float Mn = fmaxf(M, m2);
    L = L * __expf(M - Mn) + l2 * __expf(m2 - Mn);
    M = Mn;
  }
#pragma unroll
  for (int off = 1; off < 64; off <<= 1) {
    float m2 = __shfl_xor(M, off);
    float l2 = __shfl_xor(L, off);
    float Mn = fmaxf(M, m2);
    L = L * __expf(M - Mn) + l2 * __expf(m2 - Mn);
    M = Mn;
  }
  if (lane == 0) {
    float lse = M + logf(L);
    int t = tgt[row];
    rl[row] = (t != IGNORE_INDEX) ? (lse - tl[row]) : 0.f;
  }
}

// ------------------------------------------------------------- final reduce
__global__ __launch_bounds__(256)
void final_kernel(const float* __restrict__ rl, const int* __restrict__ tgt,
                  float* __restrict__ out) {
  __shared__ float ss[4];
  __shared__ float sc[4];
  float s = 0.f, c = 0.f;
  for (int r = threadIdx.x; r < BT; r += 256) {
    s += rl[r];
    c += (tgt[r] != IGNORE_INDEX) ? 1.f : 0.f;
  }
#pragma unroll
  for (int off = 32; off > 0; off >>= 1) {
    s += __shfl_xor(s, off);
    c += __shfl_xor(c, off);
  }
  int w = threadIdx.x >> 6;
  if ((threadIdx.x & 63) == 0) { ss[w] = s; sc[w] = c; }
  __syncthreads();
  if (threadIdx.x == 0) {
    float S = ss[0] + ss[1] + ss[2] + ss[3];
    float C = sc[0] + sc[1] + sc[2] + sc[3];
    out[0] = S / fmaxf(C, 1.f);
  }
}

extern "C" void kernel_launch(void* const* d_in, const int* in_sizes, int n_in,
                              void* d_out, int out_size, void* d_ws, size_t ws_size,
                              hipStream_t stream) {
  const float* hs  = (const float*)d_in[0];   // hidden_states [BT][H] fp32
  const float* wt  = (const float*)d_in[1];   // weight [V][H] fp32
  const int*   tgt = (const int*)d_in[2];     // targets [BT]
  float*       out = (float*)d_out;

  char* ws = (char*)d_ws;
  size_t off = 0;
  auto alloc = [&](size_t bytes) -> void* {
    void* p = ws + off;
    off += (bytes + 255) & ~(size_t)255;
    return p;
  };
  unsigned char* wf8 = (unsigned char*)alloc((size_t)V * H);        // 65.5 MB packed
  unsigned char* hf8 = (unsigned char*)alloc((size_t)BT * H);       // 8.4 MB packed
  float* pm = (float*)alloc((size_t)NTILES * BT * 4);               // 2.0 MB
  float* pl = (float*)alloc((size_t)NTILES * BT * 4);               // 2.0 MB
  float* tl = (float*)alloc((size_t)BT * 4);
  float* rl = (float*)alloc((size_t)BT * 4);
  (void)ws_size; (void)in_sizes; (void)n_in; (void)out_size;

  // pack tasks: one wave per (16-row group, K-tile)
  cvt_pack_kernel<<<(V / 16) * KT / 4, 256, 0, stream>>>(wt, wf8, (V / 16) * KT);
  cvt_pack_kernel<<<(BT / 16) * KT / 4, 256, 0, stream>>>(hs, hf8, (BT / 16) * KT);

  gemm_lse_kernel<<<NWG, 512, 0, stream>>>(hf8, wf8, tgt, pm, pl, tl);

  row_lse_kernel<<<BT / 4, 256, 0, stream>>>(pm, pl, tl, tgt, rl);
  final_kernel<<<1, 256, 0, stream>>>(rl, tgt, out);
}

// Round 8
// 914.857 us; speedup vs baseline: 2.8191x; 2.8191x over previous
//
#include <hip/hip_runtime.h>

#define BT 4096
#define H  2048
#define V  32000
#define BM 256
#define BN 256
#define BKB 128                   /* fp8 bytes per K-tile row */
#define KT (H / BKB)              /* 16 K-tiles */
#define NTILES (V / BN)           /* 125 */
#define MTILES (BT / BM)          /* 16 */
#define NWG (MTILES * NTILES)     /* 2000, % 8 == 0 -> bijective XCD swizzle */
#define IGNORE_INDEX (-100)

typedef int   v8i   __attribute__((ext_vector_type(8)));
typedef float f32x4 __attribute__((ext_vector_type(4)));

#define SCALE_ONE 0x7F7F7F7F        /* E8M0 127 = 2^0 in every byte */
#define UNSCALE   (1.0f / 65536.0f) /* inputs pre-scaled by 2^8 each */

#define BAR()   __builtin_amdgcn_s_barrier()
#define SB0()   __builtin_amdgcn_sched_barrier(0)
#define LGKM0() asm volatile("s_waitcnt lgkmcnt(0)" ::: "memory")
#define VMC(N)  asm volatile("s_waitcnt vmcnt(" #N ")" ::: "memory")

__device__ inline void load_lds16(const void* g, void* l) {
  __builtin_amdgcn_global_load_lds(
      (const __attribute__((address_space(1))) unsigned int*)g,
      (__attribute__((address_space(3))) unsigned int*)l,
      16, 0, 0);
}

// ------------------------------------------- fp32 -> fp8 e4m3, FRAG-PACKED
// Coalesced: wave-local LDS transpose. Per task (row-group g, K-tile kt):
// stage 16 rows x 128 floats coalesced, then each lane gathers its 32 floats
// from LDS and writes the packed 2KB block:
//   byte [c*1024 + lane*16 + b] = fp8( in[g*16 + (lane&15)]
//                                       [kt*128 + (lane>>4)*32 + c*16 + b] )
__global__ __launch_bounds__(256)
void cvt_pack_kernel(const float* __restrict__ in, unsigned char* __restrict__ out,
                     int tasks) {
  __shared__ float ld[4][16][132];           // stride 132: 2-way read (free)
  const int wv = threadIdx.x >> 6, lane = threadIdx.x & 63;
  const int task = blockIdx.x * 4 + wv;
  if (task >= tasks) return;                 // wave-divergent ok: no block bar
  const int g = task >> 4, kt = task & 15;   // KT = 16
  const float* src = in + (size_t)(g * 16) * H + kt * 128;
#pragma unroll
  for (int i = 0; i < 8; ++i) {              // 512 float4, coalesced
    int idx = i * 64 + lane;
    int r = idx >> 5, c = idx & 31;
    float4 v = *(const float4*)(src + (size_t)r * H + c * 4);
    *(float4*)&ld[wv][r][c * 4] = v;
  }
  LGKM0();                                   // cross-lane LDS visibility
  const int row = lane & 15, kb = (lane >> 4) * 32;
  int p[8];
#pragma unroll
  for (int u = 0; u < 8; ++u) {
    float4 x = *(const float4*)&ld[wv][row][kb + u * 4];
    int v = 0;
    v = __builtin_amdgcn_cvt_pk_fp8_f32(x.x * 256.f, x.y * 256.f, v, false);
    v = __builtin_amdgcn_cvt_pk_fp8_f32(x.z * 256.f, x.w * 256.f, v, true);
    p[u] = v;
  }
  unsigned char* dst = out + ((size_t)g * KT + kt) * 2048 + lane * 16;
  int4 lo; lo.x = p[0]; lo.y = p[1]; lo.z = p[2]; lo.w = p[3];
  int4 hi; hi.x = p[4]; hi.y = p[5]; hi.z = p[6]; hi.w = p[7];
  *(int4*)dst          = lo;                 // plane c=0
  *(int4*)(dst + 1024) = hi;                 // plane c=1
}

// --------------------------------------------------------------------------
// 256x256-tile, 16-wave (4x4), MX-fp8 16x16x128 MFMA, 64x64 per wave.
// Memory plan = R3/R5/R6 (proven: FETCH ~16MB, 0 conflicts): packed
// operands, contiguous-1KB global_load_lds staging, linear frag-contiguous
// LDS, frag read = base + lane*16 (+1024).
// Occupancy plan R8: 1024-thread block -> 16 waves MUST co-reside ->
// HW register cap 128/wave (compiler-enforced). Per-wave state: acc[4][4]
// = 64 (AGPR) + bf[4] = 32 + streaming A-frag 8-16 + addr ~12 < 128 ->
// no spill (R7's failure was acc[8][4]=128 under the same cap).
// 4 waves/SIMD gives the cross-wave read/MFMA overlap that the 2-wave
// lockstep of R0/R5/R6 (31% MfmaUtil invariant) could not.
// Loop = R6's 2-phase: stage other buf at phase start (4 loads/wave),
// free-scheduled reads+MFMA, VMC(0), bar. Hazards as R6 (ledger proven).
// --------------------------------------------------------------------------
union frag_u { v8i v; int4 h[2]; };

#define MF(C, A, B)                                                         \
  (C) = __builtin_amdgcn_mfma_scale_f32_16x16x128_f8f6f4(                   \
      (A).v, (B).v, (C), 0, 0, 0, SCALE_ONE, 0, SCALE_ONE)

__global__ __launch_bounds__(1024)
void gemm_lse_kernel(const unsigned char* __restrict__ Af8,
                     const unsigned char* __restrict__ Bf8,
                     const int* __restrict__ tgt,
                     float* __restrict__ pm, float* __restrict__ pl,
                     float* __restrict__ tl) {
  __shared__ __align__(16) unsigned char As[2 * 32768];  // 64 KB
  __shared__ __align__(16) unsigned char Bs[2 * 32768];  // 64 KB
  __shared__ float red_m[4][BM];
  __shared__ float red_l[4][BM];
  __shared__ int   stgt[BM];

  // T1 bijective XCD swizzle (2000 % 8 == 0), mt fastest within an XCD:
  // 16 consecutive blocks share one 512KB B-panel (L2-resident); A via L3.
  const int wgid = ((int)blockIdx.x & 7) * (NWG / 8) + ((int)blockIdx.x >> 3);
  const int mt = wgid & (MTILES - 1);
  const int nt = wgid / MTILES;
  const int m0 = mt * BM;
  const int n0 = nt * BN;

  const int tid  = threadIdx.x;
  const int lane = tid & 63;
  const int w    = tid >> 6;   // wave 0..15
  const int wr   = w >> 2;     // 0..3 : rows [wr*64, +64)
  const int wc   = w & 3;      // 0..3 : cols [wc*64, +64)
  const int lm   = lane & 15;
  const int q    = lane >> 4;

  if (tid < BM) stgt[tid] = tgt[m0 + tid];
  __syncthreads();  // drains vmcnt before counted staging begins

  // packed source: row-group (m0/16 + w), K-tile kt, 2KB contiguous.
  // wave w stages A row-group w and B row-group w (1 each, 2 loads each).
  const unsigned char* aSrc = Af8 + ((size_t)(m0 / 16 + w) * KT) * 2048;
  const unsigned char* bSrc = Bf8 + ((size_t)(n0 / 16 + w) * KT) * 2048;

  auto stageA = [&](int buf, int kt) {
    const unsigned char* s = aSrc + (size_t)kt * 2048;
    unsigned char* d = As + buf * 32768 + w * 2048;
    load_lds16(s, d);               // plane 0 (contiguous 1KB)
    load_lds16(s + 1024, d + 1024); // plane 1 (contiguous 1KB)
  };
  auto stageB = [&](int buf, int kt) {
    const unsigned char* s = bSrc + (size_t)kt * 2048;
    unsigned char* d = Bs + buf * 32768 + w * 2048;
    load_lds16(s, d);
    load_lds16(s + 1024, d + 1024);
  };

  // fragment reads: one per-lane address, immediate offsets only.
  const unsigned char* aRd = As + (wr * 4) * 2048 + lane * 16;
  const unsigned char* bRd = Bs + (wc * 4) * 2048 + lane * 16;

  auto ldA = [&](frag_u& f, int buf, int i) {
    const unsigned char* p = aRd + buf * 32768 + i * 2048;
    f.h[0] = *(const int4*)(p);
    f.h[1] = *(const int4*)(p + 1024);
  };
  auto ldB = [&](frag_u& f, int buf, int j) {
    const unsigned char* p = bRd + buf * 32768 + j * 2048;
    f.h[0] = *(const int4*)(p);
    f.h[1] = *(const int4*)(p + 1024);
  };

  f32x4 acc[4][4];
#pragma unroll
  for (int a = 0; a < 4; ++a)
#pragma unroll
    for (int b = 0; b < 4; ++b) acc[a][b] = (f32x4){0.f, 0.f, 0.f, 0.f};

  frag_u bf0, bf1, bf2, bf3;

  // ---- prologue: buf0 <- kt 0 (4 loads/wave)
  stageA(0, 0); stageB(0, 0);
  VMC(0);
  BAR();

  for (int it = 0; it < 8; ++it) {
    const int tB = 2 * it + 1;
    const bool pre = (it < 7);

    // ================= phase A: compute kt=2it from buf0, stage buf1 <- tB
    SB0();                                   // wall: nothing floats above bar
    stageA(1, tB); stageB(1, tB);
    ldB(bf0, 0, 0); ldB(bf1, 0, 1); ldB(bf2, 0, 2); ldB(bf3, 0, 3);
#pragma unroll
    for (int i = 0; i < 4; ++i) {
      frag_u fa;
      ldA(fa, 0, i);
      __builtin_amdgcn_s_setprio(1);
      MF(acc[i][0], fa, bf0); MF(acc[i][1], fa, bf1);
      MF(acc[i][2], fa, bf2); MF(acc[i][3], fa, bf3);
      __builtin_amdgcn_s_setprio(0);
    }
    VMC(0);                                  // buf1 landed (own 4 loads)
    SB0(); BAR();

    // ================= phase B: compute tB from buf1, stage buf0 <- tB+1
    SB0();
    if (pre) { stageA(0, tB + 1); stageB(0, tB + 1); }
    ldB(bf0, 1, 0); ldB(bf1, 1, 1); ldB(bf2, 1, 2); ldB(bf3, 1, 3);
#pragma unroll
    for (int i = 0; i < 4; ++i) {
      frag_u fa;
      ldA(fa, 1, i);
      __builtin_amdgcn_s_setprio(1);
      MF(acc[i][0], fa, bf0); MF(acc[i][1], fa, bf1);
      MF(acc[i][2], fa, bf2); MF(acc[i][3], fa, bf3);
      __builtin_amdgcn_s_setprio(0);
    }
    VMC(0);                                  // buf0 (tB+1) landed
    SB0(); BAR();
  }

  __syncthreads();

  // ---- target-logit extraction (C layout: col=lane&15, row=q*4+reg)
#pragma unroll
  for (int ai = 0; ai < 4; ++ai) {
#pragma unroll
    for (int r = 0; r < 4; ++r) {
      int row_local = wr * 64 + ai * 16 + q * 4 + r;
      int c = stgt[row_local] - n0 - wc * 64;
      if ((unsigned)c < 64u && (c & 15) == lm) {
        int bj = c >> 4;
        float v = bj == 0 ? acc[ai][0][r]
                : bj == 1 ? acc[ai][1][r]
                : bj == 2 ? acc[ai][2][r]
                :           acc[ai][3][r];
        tl[m0 + row_local] = v * UNSCALE;
      }
    }
  }

  // ---- per-row (max, sumexp) over this wave's 64 columns
#pragma unroll
  for (int ai = 0; ai < 4; ++ai) {
#pragma unroll
    for (int r = 0; r < 4; ++r) {
      float v0 = acc[ai][0][r] * UNSCALE;
      float v1 = acc[ai][1][r] * UNSCALE;
      float v2 = acc[ai][2][r] * UNSCALE;
      float v3 = acc[ai][3][r] * UNSCALE;
      float mx = fmaxf(fmaxf(v0, v1), fmaxf(v2, v3));
#pragma unroll
      for (int off = 1; off < 16; off <<= 1) mx = fmaxf(mx, __shfl_xor(mx, off));
      float s = __expf(v0 - mx) + __expf(v1 - mx) + __expf(v2 - mx) + __expf(v3 - mx);
#pragma unroll
      for (int off = 1; off < 16; off <<= 1) s += __shfl_xor(s, off);
      if (lm == 0) {
        int row_local = wr * 64 + ai * 16 + q * 4 + r;
        red_m[wc][row_local] = mx;
        red_l[wc][row_local] = s;
      }
    }
  }
  __syncthreads();
  if (tid < BM) {
    float M = fmaxf(fmaxf(red_m[0][tid], red_m[1][tid]),
                    fmaxf(red_m[2][tid], red_m[3][tid]));
    float L = red_l[0][tid] * __expf(red_m[0][tid] - M)
            + red_l[1][tid] * __expf(red_m[1][tid] - M)
            + red_l[2][tid] * __expf(red_m[2][tid] - M)
            + red_l[3][tid] * __expf(red_m[3][tid] - M);
    long idx = (long)nt * BT + (m0 + tid);
    pm[idx] = M;
    pl[idx] = L;
  }
}

// -------------------------------------------- combine partials, wave per row
__global__ __launch_bounds__(256)
void row_lse_kernel(const float* __restrict__ pm, const float* __restrict__ pl,
                    const float* __restrict__ tl, const int* __restrict__ tgt,
                    float* __restrict__ rl) {
  int row  = blockIdx.x * 4 + (threadIdx.x >> 6);
  int lane = threadIdx.x & 63;
  float M = -__builtin_inff();
  float L = 0.f;
  for (int t = lane; t < NTILES; t += 64) {
    float m2 = pm[(long)t * BT + row];
    float l2 = pl[(long)t * BT + row];
    float Mn = fmaxf(M, m2);
    L = L * __expf(M - Mn) + l2 * __expf(m2 - Mn);
    M = Mn;
  }
#pragma unroll
  for (int off = 1; off < 64; off <<= 1) {
    float m2 = __shfl_xor(M, off);
    float l2 = __shfl_xor(L, off);
    float Mn = fmaxf(M, m2);
    L = L * __expf(M - Mn) + l2 * __expf(m2 - Mn);
    M = Mn;
  }
  if (lane == 0) {
    float lse = M + logf(L);
    int t = tgt[row];
    rl[row] = (t != IGNORE_INDEX) ? (lse - tl[row]) : 0.f;
  }
}

// ------------------------------------------------------------- final reduce
__global__ __launch_bounds__(256)
void final_kernel(const float* __restrict__ rl, const int* __restrict__ tgt,
                  float* __restrict__ out) {
  __shared__ float ss[4];
  __shared__ float sc[4];
  float s = 0.f, c = 0.f;
  for (int r = threadIdx.x; r < BT; r += 256) {
    s += rl[r];
    c += (tgt[r] != IGNORE_INDEX) ? 1.f : 0.f;
  }
#pragma unroll
  for (int off = 32; off > 0; off >>= 1) {
    s += __shfl_xor(s, off);
    c += __shfl_xor(c, off);
  }
  int w = threadIdx.x >> 6;
  if ((threadIdx.x & 63) == 0) { ss[w] = s; sc[w] = c; }
  __syncthreads();
  if (threadIdx.x == 0) {
    float S = ss[0] + ss[1] + ss[2] + ss[3];
    float C = sc[0] + sc[1] + sc[2] + sc[3];
    out[0] = S / fmaxf(C, 1.f);
  }
}

extern "C" void kernel_launch(void* const* d_in, const int* in_sizes, int n_in,
                              void* d_out, int out_size, void* d_ws, size_t ws_size,
                              hipStream_t stream) {
  const float* hs  = (const float*)d_in[0];   // hidden_states [BT][H] fp32
  const float* wt  = (const float*)d_in[1];   // weight [V][H] fp32
  const int*   tgt = (const int*)d_in[2];     // targets [BT]
  float*       out = (float*)d_out;

  char* ws = (char*)d_ws;
  size_t off = 0;
  auto alloc = [&](size_t bytes) -> void* {
    void* p = ws + off;
    off += (bytes + 255) & ~(size_t)255;
    return p;
  };
  unsigned char* wf8 = (unsigned char*)alloc((size_t)V * H);        // 65.5 MB packed
  unsigned char* hf8 = (unsigned char*)alloc((size_t)BT * H);       // 8.4 MB packed
  float* pm = (float*)alloc((size_t)NTILES * BT * 4);               // 2.0 MB
  float* pl = (float*)alloc((size_t)NTILES * BT * 4);               // 2.0 MB
  float* tl = (float*)alloc((size_t)BT * 4);
  float* rl = (float*)alloc((size_t)BT * 4);
  (void)ws_size; (void)in_sizes; (void)n_in; (void)out_size;

  // pack tasks: one wave per (16-row group, K-tile)
  cvt_pack_kernel<<<(V / 16) * KT / 4, 256, 0, stream>>>(wt, wf8, (V / 16) * KT);
  cvt_pack_kernel<<<(BT / 16) * KT / 4, 256, 0, stream>>>(hs, hf8, (BT / 16) * KT);

  gemm_lse_kernel<<<NWG, 1024, 0, stream>>>(hf8, wf8, tgt, pm, pl, tl);

  row_lse_kernel<<<BT / 4, 256, 0, stream>>>(pm, pl, tl, tgt, rl);
  final_kernel<<<1, 256, 0, stream>>>(rl, tgt, out);
}

// Round 9
// 817.168 us; speedup vs baseline: 3.1561x; 1.1195x over previous
//
#include <hip/hip_runtime.h>

#define BT 4096
#define H  2048
#define V  32000
#define BM 256
#define BN 128
#define BKB 128                   /* fp8 bytes per K-tile row */
#define KT (H / BKB)              /* 16 K-tiles */
#define NTILES (V / BN)           /* 250 */
#define MTILES (BT / BM)          /* 16 */
#define NWG (MTILES * NTILES)     /* 4000, % 8 == 0 -> bijective XCD swizzle */
#define IGNORE_INDEX (-100)

typedef int   v8i   __attribute__((ext_vector_type(8)));
typedef float f32x4 __attribute__((ext_vector_type(4)));

#define SCALE_ONE 0x7F7F7F7F        /* E8M0 127 = 2^0 in every byte */
#define UNSCALE   (1.0f / 65536.0f) /* inputs pre-scaled by 2^8 each */

#define BAR()   __builtin_amdgcn_s_barrier()
#define SB0()   __builtin_amdgcn_sched_barrier(0)
#define LGKM0() asm volatile("s_waitcnt lgkmcnt(0)" ::: "memory")
#define VMC(N)  asm volatile("s_waitcnt vmcnt(" #N ")" ::: "memory")

__device__ inline void load_lds16(const void* g, void* l) {
  __builtin_amdgcn_global_load_lds(
      (const __attribute__((address_space(1))) unsigned int*)g,
      (__attribute__((address_space(3))) unsigned int*)l,
      16, 0, 0);
}

// ------------------------------------------- fp32 -> fp8 e4m3, FRAG-PACKED
// Coalesced: wave-local LDS transpose. Per task (row-group g, K-tile kt):
// stage 16 rows x 128 floats coalesced, then each lane gathers its 32 floats
// from LDS and writes the packed 2KB block:
//   byte [c*1024 + lane*16 + b] = fp8( in[g*16 + (lane&15)]
//                                       [kt*128 + (lane>>4)*32 + c*16 + b] )
__global__ __launch_bounds__(256)
void cvt_pack_kernel(const float* __restrict__ in, unsigned char* __restrict__ out,
                     int tasks) {
  __shared__ float ld[4][16][132];           // stride 132: 2-way read (free)
  const int wv = threadIdx.x >> 6, lane = threadIdx.x & 63;
  const int task = blockIdx.x * 4 + wv;
  if (task >= tasks) return;                 // wave-divergent ok: no block bar
  const int g = task >> 4, kt = task & 15;   // KT = 16
  const float* src = in + (size_t)(g * 16) * H + kt * 128;
#pragma unroll
  for (int i = 0; i < 8; ++i) {              // 512 float4, coalesced
    int idx = i * 64 + lane;
    int r = idx >> 5, c = idx & 31;
    float4 v = *(const float4*)(src + (size_t)r * H + c * 4);
    *(float4*)&ld[wv][r][c * 4] = v;
  }
  LGKM0();                                   // cross-lane LDS visibility
  const int row = lane & 15, kb = (lane >> 4) * 32;
  int p[8];
#pragma unroll
  for (int u = 0; u < 8; ++u) {
    float4 x = *(const float4*)&ld[wv][row][kb + u * 4];
    int v = 0;
    v = __builtin_amdgcn_cvt_pk_fp8_f32(x.x * 256.f, x.y * 256.f, v, false);
    v = __builtin_amdgcn_cvt_pk_fp8_f32(x.z * 256.f, x.w * 256.f, v, true);
    p[u] = v;
  }
  unsigned char* dst = out + ((size_t)g * KT + kt) * 2048 + lane * 16;
  int4 lo; lo.x = p[0]; lo.y = p[1]; lo.z = p[2]; lo.w = p[3];
  int4 hi; hi.x = p[4]; hi.y = p[5]; hi.z = p[6]; hi.w = p[7];
  *(int4*)dst          = lo;                 // plane c=0
  *(int4*)(dst + 1024) = hi;                 // plane c=1
}

// --------------------------------------------------------------------------
// 256x128-tile, 8-wave (4x2), 64x64 per wave, MX-fp8 16x16x128 MFMA.
// Memory plan = R3/R5/R6 (proven: FETCH ~16MB, 0 conflicts): packed
// operands, contiguous-1KB global_load_lds staging, linear frag-contiguous
// LDS, frag read = base + lane*16 (+1024).
// Pipeline plan R9: REGISTER double-buffer across K-tiles at 2 waves/SIMD.
// Corrected MFMA model: 16x16x128 MX = 8.64 cy/CU (34.5/SIMD), so per
// K-tile MFMA floor = 128 MFMA x 8.64 = 1106 cy/CU; reads must hide UNDER
// the MFMA stream, not precede it (R3/R5/R6's serial lead-in = 31% cap).
// One phase per K-tile kt (buf b = kt&1, frag sets X/Y alternate):
//   stage(buf[b], kt+2)                  // 6 gloads; buf[b]'s old frags
//                                        // were reg-captured last phase
//   ds_read frags(kt+1) <- buf[b^1]      // 8 reads, hide under MFMAs
//   16 MFMA (kt) from current reg set
//   LGKM0 ; VMC(0) ; BAR                 // reads drained; stage landed
// Hazards: overwrite of buf[b] happens >= 1 full phase + barrier after its
// frags were read (lgkm0-drained); read of buf[b^1] gated by prior phase's
// vmc0+bar. Registers: acc 64 AGPR + 2x8 frags = 128 VGPR + ~25 temps
// < 256 total -> no spill at 2 waves/SIMD (R7/R8's 4-wave attempts spilled).
// --------------------------------------------------------------------------
union frag_u { v8i v; int4 h[2]; };

#define MF(C, A, B)                                                         \
  (C) = __builtin_amdgcn_mfma_scale_f32_16x16x128_f8f6f4(                   \
      (A).v, (B).v, (C), 0, 0, 0, SCALE_ONE, 0, SCALE_ONE)

__global__ __launch_bounds__(512, 2)
void gemm_lse_kernel(const unsigned char* __restrict__ Af8,
                     const unsigned char* __restrict__ Bf8,
                     const int* __restrict__ tgt,
                     float* __restrict__ pm, float* __restrict__ pl,
                     float* __restrict__ tl) {
  __shared__ __align__(16) unsigned char As[2 * 32768];  // 64 KB (16 groups)
  __shared__ __align__(16) unsigned char Bs[2 * 16384];  // 32 KB (8 groups)
  __shared__ float red_m[2][BM];
  __shared__ float red_l[2][BM];
  __shared__ int   stgt[BM];

  // T1 bijective XCD swizzle (4000 % 8 == 0), mt fastest within an XCD:
  // 16 consecutive blocks share one 256KB B-panel (L2-resident); A via L3.
  const int wgid = ((int)blockIdx.x & 7) * (NWG / 8) + ((int)blockIdx.x >> 3);
  const int mt = wgid & (MTILES - 1);
  const int nt = wgid >> 4;          // 0..249
  const int m0 = mt * BM;
  const int n0 = nt * BN;

  const int tid  = threadIdx.x;
  const int lane = tid & 63;
  const int w    = tid >> 6;   // wave 0..7
  const int wr   = w >> 1;     // 0..3 : rows [wr*64, +64)
  const int wc   = w & 1;      // 0..1 : cols [wc*64, +64)
  const int lm   = lane & 15;
  const int q    = lane >> 4;

  if (tid < BM) stgt[tid] = tgt[m0 + tid];
  __syncthreads();  // drains vmcnt before counted staging begins

  // packed sources; wave w stages A groups {2w, 2w+1} and B group w.
  const unsigned char* aSrc = Af8 + (size_t)(m0 / 16) * KT * 2048;
  const unsigned char* bSrc = Bf8 + (size_t)(n0 / 16) * KT * 2048;

  auto stage = [&](int buf, int kt) {    // 6 gloads per wave
#pragma unroll
    for (int e = 0; e < 2; ++e) {
      const int g = 2 * w + e;
      const unsigned char* s = aSrc + ((size_t)g * KT + kt) * 2048;
      unsigned char* d = As + buf * 32768 + g * 2048;
      load_lds16(s, d);
      load_lds16(s + 1024, d + 1024);
    }
    const unsigned char* s = bSrc + ((size_t)w * KT + kt) * 2048;
    unsigned char* d = Bs + buf * 16384 + w * 2048;
    load_lds16(s, d);
    load_lds16(s + 1024, d + 1024);
  };

  // fragment reads: per-lane address + immediate offsets (conflict-free).
  const unsigned char* aRd = As + (wr * 4) * 2048 + lane * 16;
  const unsigned char* bRd = Bs + (wc * 4) * 2048 + lane * 16;

  auto ldA = [&](frag_u& f, int buf, int i) {
    const unsigned char* p = aRd + buf * 32768 + i * 2048;
    f.h[0] = *(const int4*)(p);
    f.h[1] = *(const int4*)(p + 1024);
  };
  auto ldB = [&](frag_u& f, int buf, int j) {
    const unsigned char* p = bRd + buf * 16384 + j * 2048;
    f.h[0] = *(const int4*)(p);
    f.h[1] = *(const int4*)(p + 1024);
  };

  f32x4 acc[4][4];
#pragma unroll
  for (int a = 0; a < 4; ++a)
#pragma unroll
    for (int b = 0; b < 4; ++b) acc[a][b] = (f32x4){0.f, 0.f, 0.f, 0.f};

  frag_u faX[4], fbX[4], faY[4], fbY[4];   // two named frag sets (rule #20)

#define LDSET(SET, BUF)                                                     \
  ldA(fa##SET[0], BUF, 0); ldA(fa##SET[1], BUF, 1);                         \
  ldA(fa##SET[2], BUF, 2); ldA(fa##SET[3], BUF, 3);                         \
  ldB(fb##SET[0], BUF, 0); ldB(fb##SET[1], BUF, 1);                         \
  ldB(fb##SET[2], BUF, 2); ldB(fb##SET[3], BUF, 3);

#define MFSET(SET)                                                          \
  __builtin_amdgcn_s_setprio(1);                                            \
  MF(acc[0][0], fa##SET[0], fb##SET[0]); MF(acc[1][0], fa##SET[1], fb##SET[0]); \
  MF(acc[2][0], fa##SET[2], fb##SET[0]); MF(acc[3][0], fa##SET[3], fb##SET[0]); \
  MF(acc[0][1], fa##SET[0], fb##SET[1]); MF(acc[1][1], fa##SET[1], fb##SET[1]); \
  MF(acc[2][1], fa##SET[2], fb##SET[1]); MF(acc[3][1], fa##SET[3], fb##SET[1]); \
  MF(acc[0][2], fa##SET[0], fb##SET[2]); MF(acc[1][2], fa##SET[1], fb##SET[2]); \
  MF(acc[2][2], fa##SET[2], fb##SET[2]); MF(acc[3][2], fa##SET[3], fb##SET[2]); \
  MF(acc[0][3], fa##SET[0], fb##SET[3]); MF(acc[1][3], fa##SET[1], fb##SET[3]); \
  MF(acc[2][3], fa##SET[2], fb##SET[3]); MF(acc[3][3], fa##SET[3], fb##SET[3]); \
  __builtin_amdgcn_s_setprio(0);

  // ---- prologue: buf0 <- kt0; capture X <- buf0; buf1 <- kt1
  stage(0, 0);
  VMC(0); SB0(); BAR(); SB0();
  stage(1, 1);
  LDSET(X, 0)                          // kt0 frags -> X
  LGKM0(); VMC(0); SB0(); BAR(); SB0();

  for (int it = 0; it < 8; ++it) {
    const bool pre = (it < 7);

    // ---- phase kt = 2it: MFMA(X), prefetch Y <- buf1 (kt+1), stage buf0
    if (pre) stage(0, 2 * it + 2);
    LDSET(Y, 1)                        // kt+1 frags, hide under MFMAs
    MFSET(X)
    LGKM0(); VMC(0); SB0(); BAR(); SB0();

    // ---- phase kt+1: MFMA(Y), prefetch X <- buf0 (kt+2), stage buf1
    if (pre) {
      stage(1, 2 * it + 3);
      LDSET(X, 0)                      // kt+2 frags
    }
    MFSET(Y)
    LGKM0(); VMC(0); SB0(); BAR(); SB0();
  }

  __syncthreads();

  // ---- target-logit extraction (C layout: col=lane&15, row=q*4+reg)
#pragma unroll
  for (int ai = 0; ai < 4; ++ai) {
#pragma unroll
    for (int r = 0; r < 4; ++r) {
      int row_local = wr * 64 + ai * 16 + q * 4 + r;
      int c = stgt[row_local] - n0 - wc * 64;
      if ((unsigned)c < 64u && (c & 15) == lm) {
        int bj = c >> 4;
        float v = bj == 0 ? acc[ai][0][r]
                : bj == 1 ? acc[ai][1][r]
                : bj == 2 ? acc[ai][2][r]
                :           acc[ai][3][r];
        tl[m0 + row_local] = v * UNSCALE;
      }
    }
  }

  // ---- per-row (max, sumexp) over this wave's 64 columns
#pragma unroll
  for (int ai = 0; ai < 4; ++ai) {
#pragma unroll
    for (int r = 0; r < 4; ++r) {
      float v0 = acc[ai][0][r] * UNSCALE;
      float v1 = acc[ai][1][r] * UNSCALE;
      float v2 = acc[ai][2][r] * UNSCALE;
      float v3 = acc[ai][3][r] * UNSCALE;
      float mx = fmaxf(fmaxf(v0, v1), fmaxf(v2, v3));
#pragma unroll
      for (int off = 1; off < 16; off <<= 1) mx = fmaxf(mx, __shfl_xor(mx, off));
      float s = __expf(v0 - mx) + __expf(v1 - mx) + __expf(v2 - mx) + __expf(v3 - mx);
#pragma unroll
      for (int off = 1; off < 16; off <<= 1) s += __shfl_xor(s, off);
      if (lm == 0) {
        int row_local = wr * 64 + ai * 16 + q * 4 + r;
        red_m[wc][row_local] = mx;
        red_l[wc][row_local] = s;
      }
    }
  }
  __syncthreads();
  if (tid < BM) {
    float ma = red_m[0][tid], mb = red_m[1][tid];
    float M = fmaxf(ma, mb);
    float L = red_l[0][tid] * __expf(ma - M) + red_l[1][tid] * __expf(mb - M);
    long idx = (long)nt * BT + (m0 + tid);
    pm[idx] = M;
    pl[idx] = L;
  }
}

// -------------------------------------------- combine partials, wave per row
__global__ __launch_bounds__(256)
void row_lse_kernel(const float* __restrict__ pm, const float* __restrict__ pl,
                    const float* __restrict__ tl, const int* __restrict__ tgt,
                    float* __restrict__ rl) {
  int row  = blockIdx.x * 4 + (threadIdx.x >> 6);
  int lane = threadIdx.x & 63;
  float M = -__builtin_inff();
  float L = 0.f;
  for (int t = lane; t < NTILES; t += 64) {
    float m2 = pm[(long)t * BT + row];
    float l2 = pl[(long)t * BT + row];
    float Mn = fmaxf(M, m2);
    L = L * __expf(M - Mn) + l2 * __expf(m2 - Mn);
    M = Mn;
  }
#pragma unroll
  for (int off = 1; off < 64; off <<= 1) {
    float m2 = __shfl_xor(M, off);
    float l2 = __shfl_xor(L, off);
    float Mn = fmaxf(M, m2);
    L = L * __expf(M - Mn) + l2 * __expf(m2 - Mn);
    M = Mn;
  }
  if (lane == 0) {
    float lse = M + logf(L);
    int t = tgt[row];
    rl[row] = (t != IGNORE_INDEX) ? (lse - tl[row]) : 0.f;
  }
}

// ------------------------------------------------------------- final reduce
__global__ __launch_bounds__(256)
void final_kernel(const float* __restrict__ rl, const int* __restrict__ tgt,
                  float* __restrict__ out) {
  __shared__ float ss[4];
  __shared__ float sc[4];
  float s = 0.f, c = 0.f;
  for (int r = threadIdx.x; r < BT; r += 256) {
    s += rl[r];
    c += (tgt[r] != IGNORE_INDEX) ? 1.f : 0.f;
  }
#pragma unroll
  for (int off = 32; off > 0; off >>= 1) {
    s += __shfl_xor(s, off);
    c += __shfl_xor(c, off);
  }
  int w = threadIdx.x >> 6;
  if ((threadIdx.x & 63) == 0) { ss[w] = s; sc[w] = c; }
  __syncthreads();
  if (threadIdx.x == 0) {
    float S = ss[0] + ss[1] + ss[2] + ss[3];
    float C = sc[0] + sc[1] + sc[2] + sc[3];
    out[0] = S / fmaxf(C, 1.f);
  }
}

extern "C" void kernel_launch(void* const* d_in, const int* in_sizes, int n_in,
                              void* d_out, int out_size, void* d_ws, size_t ws_size,
                              hipStream_t stream) {
  const float* hs  = (const float*)d_in[0];   // hidden_states [BT][H] fp32
  const float* wt  = (const float*)d_in[1];   // weight [V][H] fp32
  const int*   tgt = (const int*)d_in[2];     // targets [BT]
  float*       out = (float*)d_out;

  char* ws = (char*)d_ws;
  size_t off = 0;
  auto alloc = [&](size_t bytes) -> void* {
    void* p = ws + off;
    off += (bytes + 255) & ~(size_t)255;
    return p;
  };
  unsigned char* wf8 = (unsigned char*)alloc((size_t)V * H);        // 65.5 MB packed
  unsigned char* hf8 = (unsigned char*)alloc((size_t)BT * H);       // 8.4 MB packed
  float* pm = (float*)alloc((size_t)NTILES * BT * 4);               // 4.1 MB
  float* pl = (float*)alloc((size_t)NTILES * BT * 4);               // 4.1 MB
  float* tl = (float*)alloc((size_t)BT * 4);
  float* rl = (float*)alloc((size_t)BT * 4);
  (void)ws_size; (void)in_sizes; (void)n_in; (void)out_size;

  // pack tasks: one wave per (16-row group, K-tile)
  cvt_pack_kernel<<<(V / 16) * KT / 4, 256, 0, stream>>>(wt, wf8, (V / 16) * KT);
  cvt_pack_kernel<<<(BT / 16) * KT / 4, 256, 0, stream>>>(hs, hf8, (BT / 16) * KT);

  gemm_lse_kernel<<<NWG, 512, 0, stream>>>(hf8, wf8, tgt, pm, pl, tl);

  row_lse_kernel<<<BT / 4, 256, 0, stream>>>(pm, pl, tl, tgt, rl);
  final_kernel<<<1, 256, 0, stream>>>(rl, tgt, out);
}